// Round 9
// baseline (218.165 us; speedup 1.0000x reference)
//
#include <hip/hip_runtime.h>

#define B_ 256
#define T_ 512
#define C_ 256
#define L_ 64
#define S_ 129
#define CH 32        // K2 prefetch chunk (timesteps)
#define LOG2E 1.44269504f
#define LN2 0.69314718f
#define PSCALE 64.0f // 2^6: biases fp16 probs into the normal range
#define PSH 6        // log2(PSCALE); removed as 6*len in the epilogue

__device__ __forceinline__ unsigned short f2h(float f) {
    _Float16 h = (_Float16)f;
    return __builtin_bit_cast(unsigned short, h);
}
__device__ __forceinline__ float h2f(unsigned short u) {
    return (float)__builtin_bit_cast(_Float16, u);
}

template <int CTRL>
__device__ __forceinline__ int dpp_mov_i32(int x) {
    return __builtin_amdgcn_update_dpp(0, x, CTRL, 0xF, 0xF, true);
}

// f64 whole-wave shift-right-by-1 (lane l <- lane l-1; lane 0 <- +0.0).
__device__ __forceinline__ double shr1d(double x) {
    int2 u = __builtin_bit_cast(int2, x);
    u.x = dpp_mov_i32<0x138>(u.x);
    u.y = dpp_mov_i32<0x138>(u.y);
    return __builtin_bit_cast(double, u);
}

template <int CTRL>
__device__ __forceinline__ double dpp_mov_f64(double x) {
    int2 u = __builtin_bit_cast(int2, x);
    u.x = dpp_mov_i32<CTRL>(u.x);
    u.y = dpp_mov_i32<CTRL>(u.y);
    return __builtin_bit_cast(double, u);
}

// wave64 f32 sum on the VALU; total broadcast via readlane 63.
__device__ __forceinline__ float wave_sum(float x) {
#define DPPADD(ctrl)                                                          \
    x += __builtin_bit_cast(float, dpp_mov_i32<ctrl>(__builtin_bit_cast(int, x)));
    DPPADD(0x111) DPPADD(0x112) DPPADD(0x114)
    DPPADD(0x118) DPPADD(0x142) DPPADD(0x143)
#undef DPPADD
    return __builtin_bit_cast(float,
        __builtin_amdgcn_readlane(__builtin_bit_cast(int, x), 63));
}

// wave64 max of nonneg doubles, broadcast to all lanes.
__device__ __forceinline__ double wave_max_d(double x) {
    x = fmax(x, dpp_mov_f64<0x111>(x));
    x = fmax(x, dpp_mov_f64<0x112>(x));
    x = fmax(x, dpp_mov_f64<0x114>(x));
    x = fmax(x, dpp_mov_f64<0x118>(x));
    x = fmax(x, dpp_mov_f64<0x142>(x));
    x = fmax(x, dpp_mov_f64<0x143>(x));
    int2 u = __builtin_bit_cast(int2, x);
    u.x = __builtin_amdgcn_readlane(u.x, 63);
    u.y = __builtin_amdgcn_readlane(u.y, 63);
    return __builtin_bit_cast(double, u);
}

// Exact wave-wide power-of-2 rescale; accumulated exponent in e.
__device__ __forceinline__ void rescale(double& a0, double& a1, double& a2, int& e) {
    const double m = wave_max_d(fmax(fmax(a0, a1), a2));
    const int hi = __builtin_bit_cast(int2, m).y;
    int ex = ((hi >> 20) & 0x7ff) - 1023;
    if (m == 0.0) ex = 0;                 // safety (state 0 is always > 0)
    e += ex;
    int2 fb; fb.x = 0; fb.y = (1023 - ex) << 20;
    const double f = __builtin_bit_cast(double, fb);  // exact 2^-ex
    a0 *= f; a1 *= f; a2 *= f;
}

// log2 of a positive double as float: exponent + log2(mantissa).
__device__ __forceinline__ float log2_pos(double a) {
    if (a == 0.0) return -1e30f;
    int2 u = __builtin_bit_cast(int2, a);
    const int ex = ((u.y >> 20) & 0x7ff) - 1023;
    u.y = (u.y & 0x800FFFFF) | (1023 << 20);          // mantissa in [1,2)
    const float mf = (float)__builtin_bit_cast(double, u);
    return __log2f(mf) + (float)ex;
}

// ---------------------------------------------------------------------------
// K1: streaming softmax + label gather. One wave per (b,t) row, 4 waves/block,
// no __syncthreads (per-wave LDS slice) — waves free-run, VMEM stays saturated.
// Output: fp16 (p_blank, p_label[l]) * 2^6 per lane, 256 B/row.
// ---------------------------------------------------------------------------
__global__ __launch_bounds__(256) void k_soft(const float* __restrict__ logits,
                                              const int* __restrict__ targets,
                                              ushort2* __restrict__ G) {
    const int wave = threadIdx.x >> 6;
    const int lane = threadIdx.x & 63;
    const int row  = (blockIdx.x << 2) + wave;   // row = b*T + t
    const int b    = row >> 9;                   // T_ = 512

    __shared__ float sh[4][C_];                  // per-wave slice, no barrier

    const float4 v = ((const float4*)logits)[row * 64 + lane];
    float4 e;
    e.x = exp2f(v.x * LOG2E);
    e.y = exp2f(v.y * LOG2E);
    e.z = exp2f(v.z * LOG2E);
    e.w = exp2f(v.w * LOG2E);
    ((float4*)sh[wave])[lane] = e;               // stage exps for the gather

    const float s  = wave_sum(e.x + e.y + e.z + e.w);
    const float rs = PSCALE * __builtin_amdgcn_rcpf(s);
    const float eb = __builtin_bit_cast(float,
        __builtin_amdgcn_readfirstlane(__builtin_bit_cast(int, e.x)));  // class 0
    const int   tgt = targets[(b << 6) + lane];
    const float eo  = sh[wave][tgt];             // same-wave LDS: in-order, safe

    ushort2 pk;
    pk.x = f2h(eb * rs);
    pk.y = f2h(eo * rs);
    G[row * 64 + lane] = pk;
}

// ---------------------------------------------------------------------------
// K2: fp64 prob-domain alpha recurrence. One wave per batch row; lane l owns
// states 2l, 2l+1 (lane 63 also 128). Per step: shr1d + cndmask + add + mul —
// no transcendentals on the chain. 32-step double-buffered global prefetch
// (G is L2/L3-hot). Exact 2^-e rescale every 32 steps.
// ---------------------------------------------------------------------------
__global__ __launch_bounds__(64) void k_alpha(const ushort2* __restrict__ G,
                                              const int* __restrict__ targets,
                                              const int* __restrict__ in_len,
                                              const int* __restrict__ tg_len,
                                              float* __restrict__ out) {
    const int b = blockIdx.x;
    const int l = threadIdx.x;
    const ushort2* g = G + (size_t)b * T_ * 64;
    const int len = in_len[b];
    const int tl  = tg_len[b];

    const int  tc   = targets[(b << 6) + l];
    const int  tp   = __shfl_up(tc, 1);
    const bool skip = (l >= 1) && (tc != tp);

    double a0 = 0.0, a1 = 0.0, a2 = 0.0;
    int scale_total = 0;

    ushort2 bufA[CH], bufB[CH];
    #pragma unroll
    for (int j = 0; j < CH; ++j) bufA[j] = g[j * 64 + l];   // chunk 0

    for (int base = 0; base < len; base += CH) {
        #pragma unroll
        for (int j = 0; j < CH; ++j) {                       // prefetch next
            int t = base + CH + j; t = t < T_ ? t : T_ - 1;
            bufB[j] = g[t * 64 + l];
        }
        if (base == 0) {
            a0 = (l == 0) ? (double)h2f(bufA[0].x) : 0.0;    // alpha0[0]
            a1 = (l == 0) ? (double)h2f(bufA[0].y) : 0.0;    // alpha0[1]
            a2 = 0.0;
        }
        #pragma unroll
        for (int j = 0; j < CH; ++j) {
            const int t = base + j;
            if (t >= 1 && t < len) {                         // wave-uniform
                const double pb = (double)h2f(bufA[j].x);
                const double po = (double)h2f(bufA[j].y);
                const double p  = shr1d(a1);                 // alpha[2l-1]
                const double c  = skip ? p : 0.0;
                const double a0n = (a0 + p) * pb;
                const double a1n = ((a1 + a0) + c) * po;
                const double a2n = (a2 + a1) * pb;
                a0 = a0n; a1 = a1n; a2 = a2n;
            }
        }
        rescale(a0, a1, a2, scale_total);                    // every 32 steps
        #pragma unroll
        for (int j = 0; j < CH; ++j) bufA[j] = bufB[j];
    }

    __shared__ float alpha_sh[S_];
    alpha_sh[2 * l]     = log2_pos(a0);
    alpha_sh[2 * l + 1] = log2_pos(a1);
    if (l == 63) alpha_sh[128] = log2_pos(a2);
    __syncthreads();
    if (l == 0) {
        const float al = alpha_sh[2 * tl];
        const float ap = alpha_sh[2 * tl - 1];
        const float m  = fmaxf(al, ap);
        const float lse2 = m + __log2f(exp2f(al - m) + exp2f(ap - m));
        // remove the 2^6 bias: every path carries exactly `len` P-factors
        float loss = -LN2 * (lse2 + (float)scale_total - (float)(PSH * len));
        if (!(loss < 1e20f)) loss = 0.0f;        // zero_infinity (inf/nan -> 0)
        atomicAdd(out, loss / (float)tl * (1.0f / (float)B_));
    }
}

extern "C" void kernel_launch(void* const* d_in, const int* in_sizes, int n_in,
                              void* d_out, int out_size, void* d_ws, size_t ws_size,
                              hipStream_t stream) {
    const float* logits  = (const float*)d_in[0];
    const int*   targets = (const int*)d_in[1];
    const int*   in_len  = (const int*)d_in[2];
    const int*   tg_len  = (const int*)d_in[3];
    float*       out     = (float*)d_out;
    ushort2*     G       = (ushort2*)d_ws;       // 256*512*64*4 = 33.5 MB

    (void)hipMemsetAsync(d_out, 0, sizeof(float), stream);
    k_soft<<<(B_ * T_) / 4, 256, 0, stream>>>(logits, targets, G);
    k_alpha<<<B_, 64, 0, stream>>>(G, targets, in_len, tg_len, out);
}

// Round 10
// 203.253 us; speedup vs baseline: 1.0734x; 1.0734x over previous
//
#include <hip/hip_runtime.h>

#define B_ 256
#define T_ 512
#define C_ 256
#define L_ 64
#define S_ 129
#define TCH 64      // timesteps per pipelined chunk (T_/TCH = 8 chunks)
#define LOG2E 1.44269504f
#define LN2 0.69314718f

template <int CTRL>
__device__ __forceinline__ int dpp_mov_i32(int x) {
    return __builtin_amdgcn_update_dpp(0, x, CTRL, 0xF, 0xF, true);
}

// f64 whole-wave shift-right-by-1 (lane l <- lane l-1; lane 0 <- +0.0).
__device__ __forceinline__ double shr1d(double x) {
    int2 u = __builtin_bit_cast(int2, x);
    u.x = dpp_mov_i32<0x138>(u.x);
    u.y = dpp_mov_i32<0x138>(u.y);
    return __builtin_bit_cast(double, u);
}

template <int CTRL>
__device__ __forceinline__ double dpp_mov_f64(double x) {
    int2 u = __builtin_bit_cast(int2, x);
    u.x = dpp_mov_i32<CTRL>(u.x);
    u.y = dpp_mov_i32<CTRL>(u.y);
    return __builtin_bit_cast(double, u);
}

// wave64 f32 sum on the VALU; total broadcast via readlane 63.
__device__ __forceinline__ float wave_sum(float x) {
#define DPPADD(ctrl)                                                          \
    x += __builtin_bit_cast(float, dpp_mov_i32<ctrl>(__builtin_bit_cast(int, x)));
    DPPADD(0x111) DPPADD(0x112) DPPADD(0x114)
    DPPADD(0x118) DPPADD(0x142) DPPADD(0x143)
#undef DPPADD
    return __builtin_bit_cast(float,
        __builtin_amdgcn_readlane(__builtin_bit_cast(int, x), 63));
}

// wave64 max of nonneg doubles, broadcast to all lanes.
__device__ __forceinline__ double wave_max_d(double x) {
    x = fmax(x, dpp_mov_f64<0x111>(x));
    x = fmax(x, dpp_mov_f64<0x112>(x));
    x = fmax(x, dpp_mov_f64<0x114>(x));
    x = fmax(x, dpp_mov_f64<0x118>(x));
    x = fmax(x, dpp_mov_f64<0x142>(x));
    x = fmax(x, dpp_mov_f64<0x143>(x));
    int2 u = __builtin_bit_cast(int2, x);
    u.x = __builtin_amdgcn_readlane(u.x, 63);
    u.y = __builtin_amdgcn_readlane(u.y, 63);
    return __builtin_bit_cast(double, u);
}

// Exact wave-wide power-of-2 rescale; accumulated exponent in e.
__device__ __forceinline__ void rescale(double& a0, double& a1, double& a2, int& e) {
    const double m = wave_max_d(fmax(fmax(a0, a1), a2));
    const int hi = __builtin_bit_cast(int2, m).y;
    int ex = ((hi >> 20) & 0x7ff) - 1023;
    if (m == 0.0) ex = 0;                 // safety (state 0 is always > 0)
    e += ex;
    int2 fb; fb.x = 0; fb.y = (1023 - ex) << 20;
    const double f = __builtin_bit_cast(double, fb);  // exact 2^-ex
    a0 *= f; a1 *= f; a2 *= f;
}

// log2 of a positive double as float: exponent + log2(mantissa).
__device__ __forceinline__ float log2_pos(double a) {
    if (a == 0.0) return -1e30f;
    int2 u = __builtin_bit_cast(int2, a);
    const int ex = ((u.y >> 20) & 0x7ff) - 1023;
    u.y = (u.y & 0x800FFFFF) | (1023 << 20);          // mantissa in [1,2)
    const float mf = (float)__builtin_bit_cast(double, u);
    return __log2f(mf) + (float)ex;
}

// ---------------------------------------------------------------------------
// Fused kernel, barrier-free pipeline: one block per batch row, 9 waves.
// Waves 1..8 (producers): softmax in prob domain into a 2-chunk LDS ring;
//   gated only by cons_done (can run up to 2 chunks ahead). Their global
//   loads stay in flight across chunk boundaries — no vmcnt(0) drains.
// Wave 0 (consumer): fp64 prob-domain alpha recurrence; spins on prod_done.
// Sync: LDS workgroup-scope atomics (in-order LDS pipe + acq/rel).
// Single __syncthreads at init only.
// ---------------------------------------------------------------------------
__global__ __launch_bounds__(576) void k_fused(const float* __restrict__ logits,
                                               const int* __restrict__ targets,
                                               const int* __restrict__ in_len,
                                               const int* __restrict__ tg_len,
                                               float* __restrict__ out) {
    const int b = blockIdx.x;
    const int w = threadIdx.x >> 6;      // 0..8
    const int l = threadIdx.x & 63;

    __shared__ float2 P[2][TCH][64];     // (p_blank, p_odd) ring     64 KB
    __shared__ float4 rb4[8][2][64];     // per-producer-wave scratch 16 KB
    __shared__ int   tgt_sh[L_];
    __shared__ float alpha_sh[S_];
    __shared__ int   prod_done;          // producer-wave chunk completions
    __shared__ int   cons_done;          // chunks consumed

    if (threadIdx.x == 0) { prod_done = 0; cons_done = 0; }
    if (threadIdx.x < L_) tgt_sh[threadIdx.x] = targets[(b << 6) + threadIdx.x];
    __syncthreads();                     // the only block-wide barrier

    const int len = in_len[b];
    const size_t rowbase = (size_t)b * T_;

    if (w > 0) {
        // ------------------------- producer -------------------------------
        const int mytgt = tgt_sh[l];
        const int tt0 = (w - 1) * 8;
        float4 va[8], vb[8];
        #pragma unroll
        for (int r = 0; r < 8; ++r)      // chunk 0 loads in flight
            va[r] = ((const float4*)logits)[(rowbase + tt0 + r) * 64 + l];

        for (int k = 0; k < 8; ++k) {
            if (k < 7) {                 // prefetch chunk k+1 first
                #pragma unroll
                for (int r = 0; r < 8; ++r) {
                    const int t = (k + 1) * TCH + tt0 + r;
                    vb[r] = ((const float4*)logits)[(rowbase + t) * 64 + l];
                }
            }
            if (k >= 2) {                // ring slot free when chunk k-2 eaten
                while (__hip_atomic_load(&cons_done, __ATOMIC_ACQUIRE,
                                         __HIP_MEMORY_SCOPE_WORKGROUP) < k - 1) {}
            }
            #pragma unroll
            for (int r = 0; r < 8; ++r) {
                const int tt = tt0 + r;
                float4 e;
                e.x = exp2f(va[r].x * LOG2E);
                e.y = exp2f(va[r].y * LOG2E);
                e.z = exp2f(va[r].z * LOG2E);
                e.w = exp2f(va[r].w * LOG2E);
                rb4[w - 1][r & 1][l] = e;             // stage exps for gather
                const float stot = wave_sum(e.x + e.y + e.z + e.w);
                const float rs = __builtin_amdgcn_rcpf(stot);
                const float eb = __builtin_bit_cast(float,
                    __builtin_amdgcn_readfirstlane(__builtin_bit_cast(int, e.x)));
                const float eo = ((const float*)&rb4[w - 1][r & 1][0])[mytgt];
                float2 pq; pq.x = eb * rs; pq.y = eo * rs;
                P[k & 1][tt][l] = pq;
            }
            if (l == 0)                  // release: waits all LDS writes first
                __hip_atomic_fetch_add(&prod_done, 1, __ATOMIC_RELEASE,
                                       __HIP_MEMORY_SCOPE_WORKGROUP);
            #pragma unroll
            for (int r = 0; r < 8; ++r) va[r] = vb[r];
        }
        return;                          // producers exit; no tail barrier
    }

    // --------------------------- consumer (wave 0) ------------------------
    __builtin_amdgcn_s_setprio(1);
    const int tc = tgt_sh[l];
    const int tp = __shfl_up(tc, 1);
    const bool skip = (l >= 1) && (tc != tp);
    const int tl = tg_len[b];

    double a0 = 0.0, a1 = 0.0, a2 = 0.0;
    int scale_total = 0;

    for (int k = 0; k < 8; ++k) {
        while (__hip_atomic_load(&prod_done, __ATOMIC_ACQUIRE,
                                 __HIP_MEMORY_SCOPE_WORKGROUP) < 8 * (k + 1)) {}
        const int kb = k & 1;
        const int base = k * TCH;
        float2 pa[8], pn[8];
        #pragma unroll
        for (int j = 0; j < 8; ++j) pa[j] = P[kb][j][l];
        if (k == 0) {
            a0 = (l == 0) ? (double)pa[0].x : 0.0;   // alpha0[0]
            a1 = (l == 0) ? (double)pa[0].y : 0.0;   // alpha0[1]
            a2 = 0.0;
        }
        for (int g = 0; g < 8; ++g) {
            if (g < 7) {
                #pragma unroll
                for (int j = 0; j < 8; ++j) pn[j] = P[kb][(g + 1) * 8 + j][l];
            }
            #pragma unroll
            for (int j = 0; j < 8; ++j) {
                const int t = base + g * 8 + j;
                if (t >= 1 && t < len) {             // wave-uniform guard
                    const double p = shr1d(a1);      // alpha[2l-1]
                    const double c = skip ? p : 0.0;
                    const double a0n = (a0 + p) * (double)pa[j].x;
                    const double a1n = ((a1 + a0) + c) * (double)pa[j].y;
                    const double a2n = (a2 + a1) * (double)pa[j].x;
                    a0 = a0n; a1 = a1n; a2 = a2n;
                }
            }
            if (g == 3 || g == 7) rescale(a0, a1, a2, scale_total);
            if (g < 7) {
                #pragma unroll
                for (int j = 0; j < 8; ++j) pa[j] = pn[j];
            }
        }
        if (l == 0)
            __hip_atomic_fetch_add(&cons_done, 1, __ATOMIC_RELEASE,
                                   __HIP_MEMORY_SCOPE_WORKGROUP);
    }

    // epilogue entirely within wave 0 (in-order LDS pipe: no barrier needed)
    alpha_sh[2 * l]     = log2_pos(a0);
    alpha_sh[2 * l + 1] = log2_pos(a1);
    if (l == 63) alpha_sh[128] = log2_pos(a2);
    if (l == 0) {
        const float al = alpha_sh[2 * tl];
        const float ap = alpha_sh[2 * tl - 1];
        const float m  = fmaxf(al, ap);
        const float lse2 = m + __log2f(exp2f(al - m) + exp2f(ap - m));
        float loss = -LN2 * (lse2 + (float)scale_total);
        if (!(loss < 1e20f)) loss = 0.0f;        // zero_infinity (inf/nan -> 0)
        atomicAdd(out, loss / (float)tl * (1.0f / (float)B_));
    }
}

extern "C" void kernel_launch(void* const* d_in, const int* in_sizes, int n_in,
                              void* d_out, int out_size, void* d_ws, size_t ws_size,
                              hipStream_t stream) {
    const float* logits  = (const float*)d_in[0];
    const int*   targets = (const int*)d_in[1];
    const int*   in_len  = (const int*)d_in[2];
    const int*   tg_len  = (const int*)d_in[3];
    float*       out     = (float*)d_out;

    (void)hipMemsetAsync(d_out, 0, sizeof(float), stream);
    k_fused<<<B_, 576, 0, stream>>>(logits, targets, in_len, tg_len, out);
}

// Round 11
// 202.144 us; speedup vs baseline: 1.0793x; 1.0055x over previous
//
#include <hip/hip_runtime.h>

#define B_ 256
#define T_ 512
#define C_ 256
#define L_ 64
#define S_ 129
#define TCH 64      // timesteps per pipelined chunk (T_/TCH = 8 chunks)
#define NRING 3     // LDS ring depth (chunks)
#define LOG2E 1.44269504f
#define LN2 0.69314718f

template <int CTRL>
__device__ __forceinline__ int dpp_mov_i32(int x) {
    return __builtin_amdgcn_update_dpp(0, x, CTRL, 0xF, 0xF, true);
}

// f64 whole-wave shift-right-by-1 (lane l <- lane l-1; lane 0 <- +0.0).
__device__ __forceinline__ double shr1d(double x) {
    int2 u = __builtin_bit_cast(int2, x);
    u.x = dpp_mov_i32<0x138>(u.x);
    u.y = dpp_mov_i32<0x138>(u.y);
    return __builtin_bit_cast(double, u);
}

template <int CTRL>
__device__ __forceinline__ double dpp_mov_f64(double x) {
    int2 u = __builtin_bit_cast(int2, x);
    u.x = dpp_mov_i32<CTRL>(u.x);
    u.y = dpp_mov_i32<CTRL>(u.y);
    return __builtin_bit_cast(double, u);
}

// wave64 f32 sum on the VALU; total broadcast via readlane 63.
__device__ __forceinline__ float wave_sum(float x) {
#define DPPADD(ctrl)                                                          \
    x += __builtin_bit_cast(float, dpp_mov_i32<ctrl>(__builtin_bit_cast(int, x)));
    DPPADD(0x111) DPPADD(0x112) DPPADD(0x114)
    DPPADD(0x118) DPPADD(0x142) DPPADD(0x143)
#undef DPPADD
    return __builtin_bit_cast(float,
        __builtin_amdgcn_readlane(__builtin_bit_cast(int, x), 63));
}

// wave64 max of nonneg doubles, broadcast to all lanes.
__device__ __forceinline__ double wave_max_d(double x) {
    x = fmax(x, dpp_mov_f64<0x111>(x));
    x = fmax(x, dpp_mov_f64<0x112>(x));
    x = fmax(x, dpp_mov_f64<0x114>(x));
    x = fmax(x, dpp_mov_f64<0x118>(x));
    x = fmax(x, dpp_mov_f64<0x142>(x));
    x = fmax(x, dpp_mov_f64<0x143>(x));
    int2 u = __builtin_bit_cast(int2, x);
    u.x = __builtin_amdgcn_readlane(u.x, 63);
    u.y = __builtin_amdgcn_readlane(u.y, 63);
    return __builtin_bit_cast(double, u);
}

// Exact wave-wide power-of-2 rescale; accumulated exponent in e.
__device__ __forceinline__ void rescale(double& a0, double& a1, double& a2, int& e) {
    const double m = wave_max_d(fmax(fmax(a0, a1), a2));
    const int hi = __builtin_bit_cast(int2, m).y;
    int ex = ((hi >> 20) & 0x7ff) - 1023;
    if (m == 0.0) ex = 0;                 // safety (state 0 is always > 0)
    e += ex;
    int2 fb; fb.x = 0; fb.y = (1023 - ex) << 20;
    const double f = __builtin_bit_cast(double, fb);  // exact 2^-ex
    a0 *= f; a1 *= f; a2 *= f;
}

// log2 of a positive double as float: exponent + log2(mantissa).
__device__ __forceinline__ float log2_pos(double a) {
    if (a == 0.0) return -1e30f;
    int2 u = __builtin_bit_cast(int2, a);
    const int ex = ((u.y >> 20) & 0x7ff) - 1023;
    u.y = (u.y & 0x800FFFFF) | (1023 << 20);          // mantissa in [1,2)
    const float mf = (float)__builtin_bit_cast(double, u);
    return __log2f(mf) + (float)ex;
}

// ---------------------------------------------------------------------------
// Fused kernel, barrier-free pipeline: one block per batch row, 9 waves.
// Waves 1..8 (producers): softmax in prob domain into a 3-chunk LDS ring.
// Wave 0 (consumer): fp64 prob-domain alpha recurrence with a SHORT serial
//   chain: per step only shr1d -> cndmask -> add -> mul; the sums s01=a1+a0,
//   s12=a2+a1 are computed at step end, in parallel with the next shr1d.
//   No per-step branches (len is block-uniform; chunk split into full
//   8-groups + one guarded partial group). Exact 2^-e rescale every 32 steps.
// ---------------------------------------------------------------------------
__global__ __launch_bounds__(576) void k_fused(const float* __restrict__ logits,
                                               const int* __restrict__ targets,
                                               const int* __restrict__ in_len,
                                               const int* __restrict__ tg_len,
                                               float* __restrict__ out) {
    const int b = blockIdx.x;
    const int w = threadIdx.x >> 6;      // 0..8
    const int l = threadIdx.x & 63;

    __shared__ float2 P[NRING][TCH][64]; // (p_blank, p_odd) ring     96 KB
    __shared__ float4 rb4[8][2][64];     // per-producer-wave scratch 16 KB
    __shared__ int   tgt_sh[L_];
    __shared__ float alpha_sh[S_];
    __shared__ int   prod_done;          // producer-wave chunk completions
    __shared__ int   cons_done;          // chunks consumed

    if (threadIdx.x == 0) { prod_done = 0; cons_done = 0; }
    if (threadIdx.x < L_) tgt_sh[threadIdx.x] = targets[(b << 6) + threadIdx.x];
    __syncthreads();                     // the only block-wide barrier

    const int len = in_len[b];
    const size_t rowbase = (size_t)b * T_;

    if (w > 0) {
        // ------------------------- producer -------------------------------
        const int mytgt = tgt_sh[l];
        const int tt0 = (w - 1) * 8;
        float4 va[8], vb[8];
        #pragma unroll
        for (int r = 0; r < 8; ++r)      // chunk 0 loads in flight
            va[r] = ((const float4*)logits)[(rowbase + tt0 + r) * 64 + l];

        int kb = 0;
        for (int k = 0; k < 8; ++k) {
            if (k < 7) {                 // prefetch chunk k+1 first
                #pragma unroll
                for (int r = 0; r < 8; ++r) {
                    const int t = (k + 1) * TCH + tt0 + r;
                    vb[r] = ((const float4*)logits)[(rowbase + t) * 64 + l];
                }
            }
            if (k >= NRING) {            // ring slot free when k-NRING eaten
                while (__hip_atomic_load(&cons_done, __ATOMIC_ACQUIRE,
                                         __HIP_MEMORY_SCOPE_WORKGROUP) < k - (NRING - 1))
                    __builtin_amdgcn_s_sleep(2);
            }
            #pragma unroll
            for (int r = 0; r < 8; ++r) {
                const int tt = tt0 + r;
                float4 e;
                e.x = exp2f(va[r].x * LOG2E);
                e.y = exp2f(va[r].y * LOG2E);
                e.z = exp2f(va[r].z * LOG2E);
                e.w = exp2f(va[r].w * LOG2E);
                rb4[w - 1][r & 1][l] = e;             // stage exps for gather
                const float stot = wave_sum(e.x + e.y + e.z + e.w);
                const float rs = __builtin_amdgcn_rcpf(stot);
                const float eb = __builtin_bit_cast(float,
                    __builtin_amdgcn_readfirstlane(__builtin_bit_cast(int, e.x)));
                const float eo = ((const float*)&rb4[w - 1][r & 1][0])[mytgt];
                float2 pq; pq.x = eb * rs; pq.y = eo * rs;
                P[kb][tt][l] = pq;
            }
            if (l == 0)                  // release: waits all LDS writes first
                __hip_atomic_fetch_add(&prod_done, 1, __ATOMIC_RELEASE,
                                       __HIP_MEMORY_SCOPE_WORKGROUP);
            #pragma unroll
            for (int r = 0; r < 8; ++r) va[r] = vb[r];
            if (++kb == NRING) kb = 0;
        }
        return;                          // producers exit; no tail barrier
    }

    // --------------------------- consumer (wave 0) ------------------------
    __builtin_amdgcn_s_setprio(1);
    const int tc = tgt_sh[l];
    const int tp = __shfl_up(tc, 1);
    const bool skip = (l >= 1) && (tc != tp);
    const int tl = tg_len[b];

    double a0 = 0.0, a1 = 0.0, a2 = 0.0, s01 = 0.0, s12 = 0.0;
    int scale_total = 0;

    // one step; chain: shr1d -> cndmask -> add -> mul (s01/s12 off-path)
#define STEP(pb, po)                                                          \
    {                                                                         \
        const double p = shr1d(a1);                                           \
        const double c = skip ? p : 0.0;                                      \
        const double a0n = (a0 + p) * (pb);                                   \
        const double a1n = (s01 + c) * (po);                                  \
        const double a2n = s12 * (pb);                                        \
        a0 = a0n; a1 = a1n; a2 = a2n;                                         \
        s01 = a1n + a0n; s12 = a2n + a1n;                                     \
    }

    int kb = 0;
    for (int k = 0; k < 8; ++k) {
        while (__hip_atomic_load(&prod_done, __ATOMIC_ACQUIRE,
                                 __HIP_MEMORY_SCOPE_WORKGROUP) < 8 * (k + 1))
            __builtin_amdgcn_s_sleep(2);
        const int base = k * TCH;
        const int rem  = len - base;
        const int lim  = rem > TCH ? TCH : (rem < 0 ? 0 : rem);   // uniform

        for (int g = 0; g < 8; ++g) {
            const int gb = g * 8;
            float2 pa[8];
            #pragma unroll
            for (int j = 0; j < 8; ++j) pa[j] = P[kb][gb + j][l];
            double pbd[8], pod[8];
            #pragma unroll
            for (int j = 0; j < 8; ++j) {
                pbd[j] = (double)pa[j].x;
                pod[j] = (double)pa[j].y;
            }
            if (k == 0 && g == 0) {
                a0 = (l == 0) ? pbd[0] : 0.0;    // alpha0[0]
                a1 = (l == 0) ? pod[0] : 0.0;    // alpha0[1]
                a2 = 0.0; s01 = a0 + a1; s12 = a1;
                #pragma unroll
                for (int j = 1; j < 8; ++j) STEP(pbd[j], pod[j])
            } else if (gb + 8 <= lim) {          // full group, no guards
                #pragma unroll
                for (int j = 0; j < 8; ++j) STEP(pbd[j], pod[j])
            } else if (gb < lim) {               // partial group (last chunk)
                const int cnt = lim - gb;
                for (int j = 0; j < cnt; ++j) STEP(pbd[j], pod[j])
            }
            if (g == 3 || g == 7) {
                rescale(a0, a1, a2, scale_total);
                s01 = a1 + a0; s12 = a2 + a1;
            }
        }
        if (l == 0)
            __hip_atomic_fetch_add(&cons_done, 1, __ATOMIC_RELEASE,
                                   __HIP_MEMORY_SCOPE_WORKGROUP);
        if (++kb == NRING) kb = 0;
    }
#undef STEP

    // epilogue entirely within wave 0 (in-order LDS pipe: no barrier needed)
    alpha_sh[2 * l]     = log2_pos(a0);
    alpha_sh[2 * l + 1] = log2_pos(a1);
    if (l == 63) alpha_sh[128] = log2_pos(a2);
    if (l == 0) {
        const float al = alpha_sh[2 * tl];
        const float ap = alpha_sh[2 * tl - 1];
        const float m  = fmaxf(al, ap);
        const float lse2 = m + __log2f(exp2f(al - m) + exp2f(ap - m));
        float loss = -LN2 * (lse2 + (float)scale_total);
        if (!(loss < 1e20f)) loss = 0.0f;        // zero_infinity (inf/nan -> 0)
        atomicAdd(out, loss / (float)tl * (1.0f / (float)B_));
    }
}

extern "C" void kernel_launch(void* const* d_in, const int* in_sizes, int n_in,
                              void* d_out, int out_size, void* d_ws, size_t ws_size,
                              hipStream_t stream) {
    const float* logits  = (const float*)d_in[0];
    const int*   targets = (const int*)d_in[1];
    const int*   in_len  = (const int*)d_in[2];
    const int*   tg_len  = (const int*)d_in[3];
    float*       out     = (float*)d_out;

    (void)hipMemsetAsync(d_out, 0, sizeof(float), stream);
    k_fused<<<B_, 576, 0, stream>>>(logits, targets, in_len, tg_len, out);
}